// Round 2
// baseline (130583.704 us; speedup 1.0000x reference)
//
#include <hip/hip_runtime.h>
#include <hip/hip_bf16.h>

#define T_STEPS 4096
#define BATCH 8
#define DIN 512
#define NH 512
#define G4 2048
#define NBLK 16
#define WPB 8

typedef __attribute__((ext_vector_type(8))) short bf16x8;
typedef __attribute__((ext_vector_type(4))) float f32x4;
typedef __attribute__((ext_vector_type(4))) int i32x4;

__device__ __forceinline__ unsigned short f2b(float f) {
  __hip_bfloat16 h = __float2bfloat16(f);
  return __builtin_bit_cast(unsigned short, h);
}
__device__ __forceinline__ float b2f(unsigned short u) {
  unsigned int x = ((unsigned int)u) << 16;
  return __builtin_bit_cast(float, x);
}
__device__ __forceinline__ float sigf(float x) { return 1.f / (1.f + __expf(-x)); }
__device__ __forceinline__ float tanh_fast(float x) { return 1.f - 2.f / (1.f + __expf(2.f * x)); }

// mailbox: u64 [2 parity][8 b][256 jp]; slot = (tag<<32) | (bf16 h[2jp+1])<<16 | bf16 h[2jp]
__global__ __launch_bounds__(512) void init_ws(const float* __restrict__ h0,
                                               unsigned long long* __restrict__ mbox) {
  int tid = threadIdx.x;
  for (int i = tid; i < 2048; i += 512) {
    int b = i >> 8, jp = i & 255;
    unsigned int pk = ((unsigned int)f2b(h0[b * NH + 2 * jp + 1]) << 16) |
                      f2b(h0[b * NH + 2 * jp]);
    mbox[i] = (unsigned long long)pk;            // parity 0, tag 0
    mbox[2048 + i] = 0xFFFFFFFFull << 32;        // parity 1, poison tag
  }
}

// ---------------- XI = x @ Wi + (bi + bh), pre-swizzled to [t][wv(128)][lane(32)][q(4)] u16
#define BM 64
#define BN 64
#define BK 16
__global__ __launch_bounds__(256) void xi_gemm(const float* __restrict__ x,
                                               const float* __restrict__ Wi,
                                               const float* __restrict__ bi,
                                               const float* __restrict__ bh,
                                               unsigned short* __restrict__ xi3) {
  __shared__ float As[BK][BM + 4];
  __shared__ float Bs[BK][BN + 4];
  const int tid = threadIdx.x;
  const int m0 = blockIdx.x * BM;
  const int n0 = blockIdx.y * BN;
  const int tx = tid & 15, ty = tid >> 4;
  const int arow = tid & 63, ak = (tid >> 6) << 2;
  const int bk = tid >> 4, bn = (tid & 15) << 2;
  float acc[4][4] = {};
  for (int k0 = 0; k0 < DIN; k0 += BK) {
    float4 av = *(const float4*)(x + (size_t)(m0 + arow) * DIN + k0 + ak);
    float4 bv = *(const float4*)(Wi + (size_t)(k0 + bk) * G4 + n0 + bn);
    __syncthreads();
    As[ak + 0][arow] = av.x;
    As[ak + 1][arow] = av.y;
    As[ak + 2][arow] = av.z;
    As[ak + 3][arow] = av.w;
    *(float4*)&Bs[bk][bn] = bv;
    __syncthreads();
#pragma unroll
    for (int kk = 0; kk < BK; ++kk) {
      float am[4], bw[4];
      *(float4*)am = *(const float4*)&As[kk][ty << 2];
      *(float4*)bw = *(const float4*)&Bs[kk][tx << 2];
#pragma unroll
      for (int i = 0; i < 4; ++i)
#pragma unroll
        for (int j = 0; j < 4; ++j) acc[i][j] = fmaf(am[i], bw[j], acc[i][j]);
    }
  }
  // epilogue: swizzled store. thread rows m = m0+ty*4+i (q=i), cols n = n0+tx*4+j
  const int m_base = m0 + (ty << 2);
  const int n_base = n0 + (tx << 2);
  const int tt = m_base >> 3;
  const int rg = (m_base & 7) >> 2;
  const int gate = n_base >> 9;
  const int wv = (n_base & 511) >> 2;
  unsigned long long vj[4];
#pragma unroll
  for (int j = 0; j < 4; ++j) {
    int n = n_base + j;
    float bs = bi[n] + bh[n];
    unsigned long long e0 = f2b(acc[0][j] + bs);
    unsigned long long e1 = f2b(acc[1][j] + bs);
    unsigned long long e2 = f2b(acc[2][j] + bs);
    unsigned long long e3 = f2b(acc[3][j] + bs);
    vj[j] = (e3 << 48) | (e2 << 32) | (e1 << 16) | e0;
  }
  size_t u16base = ((size_t)(tt * 128 + wv) * 32 + rg * 16 + gate * 4) * 4;
  uint4 lo = {(unsigned int)vj[0], (unsigned int)(vj[0] >> 32),
              (unsigned int)vj[1], (unsigned int)(vj[1] >> 32)};
  uint4 hi = {(unsigned int)vj[2], (unsigned int)(vj[2] >> 32),
              (unsigned int)vj[3], (unsigned int)(vj[3] >> 32)};
  *(uint4*)(xi3 + u16base) = lo;
  *(uint4*)(xi3 + u16base + 8) = hi;
}

// ---------------- persistent recurrence: 16 blocks x 8 waves = 128 independent waves.
// wave wv owns j cols [wv*4, wv*4+4), ALL 4 gates. No LDS, no __syncthreads.
__global__ __launch_bounds__(512, 2) void lstm_rec(const float* __restrict__ Wh,
                                                   const float* __restrict__ h0c0,
                                                   const unsigned long long* __restrict__ xi3,
                                                   float* __restrict__ out,
                                                   unsigned long long* __restrict__ mbox) {
  const int tid = threadIdx.x;
  const int lane = tid & 63;
  const int w = tid >> 6;
  const int wv = blockIdx.x * WPB + w;
  const int j0w = wv << 2;
  const int v = lane & 15;        // C/B virtual col: gate = v>>2, jl = v&3
  const int rg = lane >> 4;       // C row group (batch b = rg*4+q)
  const int ab = lane & 15;       // A row = batch
  const int kq = lane >> 4;       // A k sub-block

  // ---- preload B fragments: Wh[k][gate*512 + j0w + jl], k = ks*32 + kq*8 + e
  bf16x8 bw[16];
  {
    const int bcol = ((v >> 2) << 9) + j0w + (v & 3);
#pragma unroll
    for (int ks = 0; ks < 16; ++ks) {
      bf16x8 tmp;
#pragma unroll
      for (int e = 0; e < 8; ++e)
        tmp[e] = (short)f2b(Wh[(size_t)(ks * 32 + kq * 8 + e) * G4 + bcol]);
      bw[ks] = tmp;
    }
  }

  // ---- cell init (meaningful lanes: v<4, rg<2)
  const bool act = (v < 4) && (rg < 2);
  f32x4 cell = {0.f, 0.f, 0.f, 0.f};
  if (act) {
#pragma unroll
    for (int q = 0; q < 4; ++q)
      cell[q] = h0c0[(size_t)(BATCH + rg * 4 + q) * NH + j0w + v];
  }

  // ---- XI prefetch (t=0): one u64 per lane<32
  const unsigned long long* xw = xi3 + (size_t)wv * 32 + lane;
  unsigned long long xiCur = (lane < 32) ? xw[0] : 0ull;

  const bool ldok = (ab < 8);
  const int abase = ab * 256 + kq * 4;
  float hq[4] = {0.f, 0.f, 0.f, 0.f};

  for (int t = 0; t < T_STEPS; ++t) {
    const unsigned long long* mb = mbox + ((size_t)(t & 1) << 11);
    const unsigned int tgt = (unsigned int)t;

    // ---- poll h(t): 64 tagged u64 slots per lane (b<8 lanes)
    unsigned long long qq[16][4];
#pragma unroll
    for (int ks = 0; ks < 16; ++ks)
#pragma unroll
      for (int s = 0; s < 4; ++s)
        qq[ks][s] = ldok ? __hip_atomic_load(mb + abase + ks * 16 + s, __ATOMIC_RELAXED,
                                             __HIP_MEMORY_SCOPE_AGENT)
                         : 0ull;
    for (;;) {
      unsigned int bad = 0u;
#pragma unroll
      for (int ks = 0; ks < 16; ++ks)
#pragma unroll
        for (int s = 0; s < 4; ++s) bad |= ((unsigned int)(qq[ks][s] >> 32)) ^ tgt;
      int okl = (!ldok) || (bad == 0u);
      if (__all(okl)) break;
#pragma unroll
      for (int ks = 0; ks < 16; ++ks)
#pragma unroll
        for (int s = 0; s < 4; ++s)
          if (ldok)
            qq[ks][s] = __hip_atomic_load(mb + abase + ks * 16 + s, __ATOMIC_RELAXED,
                                          __HIP_MEMORY_SCOPE_AGENT);
    }

    // ---- issue XI(t+1) prefetch now (completes during gates+publish+next poll)
    unsigned long long xiNext = 0ull;
    if (t + 1 < T_STEPS && lane < 32) xiNext = xw[(size_t)(t + 1) * 4096];

    // ---- MFMA: 16 k-steps, 2 interleaved chains; acc0 seeded with XI
    f32x4 acc0 = {0.f, 0.f, 0.f, 0.f};
    if (lane < 32) {
#pragma unroll
      for (int q = 0; q < 4; ++q) acc0[q] = b2f((unsigned short)(xiCur >> (16 * q)));
    }
    f32x4 acc1 = {0.f, 0.f, 0.f, 0.f};
#pragma unroll
    for (int ks = 0; ks < 16; ks += 2) {
      i32x4 p0 = {(int)(unsigned int)qq[ks][0], (int)(unsigned int)qq[ks][1],
                  (int)(unsigned int)qq[ks][2], (int)(unsigned int)qq[ks][3]};
      i32x4 p1 = {(int)(unsigned int)qq[ks + 1][0], (int)(unsigned int)qq[ks + 1][1],
                  (int)(unsigned int)qq[ks + 1][2], (int)(unsigned int)qq[ks + 1][3]};
      bf16x8 a0 = __builtin_bit_cast(bf16x8, p0);
      bf16x8 a1 = __builtin_bit_cast(bf16x8, p1);
      acc0 = __builtin_amdgcn_mfma_f32_16x16x32_bf16(a0, bw[ks], acc0, 0, 0, 0);
      acc1 = __builtin_amdgcn_mfma_f32_16x16x32_bf16(a1, bw[ks + 1], acc1, 0, 0, 0);
    }
    f32x4 pre = acc0 + acc1;   // pre[gate(v>>2)][j0w+(v&3)][b=rg*4+q]

    // ---- gather 4 gates into v<4 lanes via intra-wave shuffles (all lanes execute)
    f32x4 pi, po, pg;
#pragma unroll
    for (int q = 0; q < 4; ++q) {
      pi[q] = __shfl_xor(pre[q], 4);
      po[q] = __shfl_xor(pre[q], 8);
      pg[q] = __shfl_xor(pre[q], 12);
    }
#pragma unroll
    for (int q = 0; q < 4; ++q) {
      float fg = sigf(pre[q]);
      float ig = sigf(pi[q]);
      float og = sigf(po[q]);
      float gg = tanh_fast(pg[q]);
      float cn = fg * cell[q] + ig * gg;
      cell[q] = cn;
      hq[q] = og * tanh_fast(cn);
    }
    // ---- pair cols for publish (v even gets v+1's h)
    float hp[4];
#pragma unroll
    for (int q = 0; q < 4; ++q) hp[q] = __shfl_xor(hq[q], 1);

    if (act && ((v & 1) == 0)) {
      unsigned long long* mpub = mbox + ((size_t)((t + 1) & 1) << 11);
      const int jp = (j0w >> 1) + (v >> 1);
#pragma unroll
      for (int q = 0; q < 4; ++q) {
        unsigned long long val = ((unsigned long long)(unsigned int)(t + 1) << 32) |
                                 ((unsigned long long)f2b(hp[q]) << 16) | f2b(hq[q]);
        __hip_atomic_store(mpub + (rg * 4 + q) * 256 + jp, val, __ATOMIC_RELAXED,
                           __HIP_MEMORY_SCOPE_AGENT);
      }
    }
    if (act) {
#pragma unroll
      for (int q = 0; q < 4; ++q)
        out[((size_t)t * BATCH + rg * 4 + q) * NH + j0w + v] = hq[q];
    }
    xiCur = xiNext;
  }

  // ---- final state tail: [h_T ; c_T]
  if (act) {
    const size_t tail = (size_t)T_STEPS * BATCH * NH;
#pragma unroll
    for (int q = 0; q < 4; ++q) {
      out[tail + (size_t)(rg * 4 + q) * NH + j0w + v] = hq[q];
      out[tail + (size_t)BATCH * NH + (size_t)(rg * 4 + q) * NH + j0w + v] = cell[q];
    }
  }
}

extern "C" void kernel_launch(void* const* d_in, const int* in_sizes, int n_in,
                              void* d_out, int out_size, void* d_ws, size_t ws_size,
                              hipStream_t stream) {
  const float* x  = (const float*)d_in[0];
  const float* h0 = (const float*)d_in[1];
  const float* Wi = (const float*)d_in[2];
  const float* bi = (const float*)d_in[3];
  const float* Wh = (const float*)d_in[4];
  const float* bh = (const float*)d_in[5];
  float* out = (float*)d_out;

  // ws: [0, 32KB) mailbox u64[2][2048] | [64KB, +134.25MB) xi3
  unsigned long long* mbox = (unsigned long long*)d_ws;
  unsigned short* xi3 = (unsigned short*)((char*)d_ws + 65536);

  init_ws<<<1, 512, 0, stream>>>(h0, mbox);
  dim3 g1((T_STEPS * BATCH) / BM, G4 / BN);
  xi_gemm<<<g1, 256, 0, stream>>>(x, Wi, bi, bh, xi3);
  lstm_rec<<<NBLK, 512, 0, stream>>>(Wh, h0, (const unsigned long long*)xi3, out, mbox);
}

// Round 3
// 19618.547 us; speedup vs baseline: 6.6561x; 6.6561x over previous
//
#include <hip/hip_runtime.h>
#include <hip/hip_bf16.h>

#define T_STEPS 4096
#define BATCH 8
#define DIN 512
#define NH 512
#define G4 2048
#define NWV 32
#define JPW 16

typedef __attribute__((ext_vector_type(8))) short bf16x8;
typedef __attribute__((ext_vector_type(4))) float f32x4;

__device__ __forceinline__ unsigned short f2b(float f) {
  __hip_bfloat16 h = __float2bfloat16(f);
  return __builtin_bit_cast(unsigned short, h);
}
__device__ __forceinline__ float b2f(unsigned short u) {
  unsigned int x = ((unsigned int)u) << 16;
  return __builtin_bit_cast(float, x);
}
__device__ __forceinline__ float sigf(float x) { return 1.f / (1.f + __expf(-x)); }
__device__ __forceinline__ float tanh_fast(float x) { return 1.f - 2.f / (1.f + __expf(2.f * x)); }

// ---------------- init: tags=0; hbuf parity0 = bf16(h0), parity1 = 0
__global__ __launch_bounds__(512) void init_ws(const float* __restrict__ h0,
                                               unsigned int* __restrict__ tags,
                                               unsigned short* __restrict__ hbuf) {
  int tid = threadIdx.x;
  if (tid < NWV) tags[tid] = 0u;
  for (int i = tid; i < 4096; i += 512) {   // [8 b][512 j] per parity
    int b = i >> 9, j = i & 511;
    hbuf[i] = f2b(h0[b * NH + j]);
    hbuf[4096 + i] = 0;
  }
}

// ---------------- XI = x @ Wi + (bi + bh), swizzled to [t][wv][lane(32)][g*4+q] u16
#define BM 64
#define BN 64
#define BK 16
__global__ __launch_bounds__(256) void xi_gemm(const float* __restrict__ x,
                                               const float* __restrict__ Wi,
                                               const float* __restrict__ bi,
                                               const float* __restrict__ bh,
                                               unsigned short* __restrict__ xi) {
  __shared__ float As[BK][BM + 4];
  __shared__ float Bs[BK][BN + 4];
  const int tid = threadIdx.x;
  const int m0 = blockIdx.x * BM;
  const int n0 = blockIdx.y * BN;
  const int tx = tid & 15, ty = tid >> 4;
  const int arow = tid & 63, ak = (tid >> 6) << 2;
  const int bk = tid >> 4, bn = (tid & 15) << 2;
  float acc[4][4] = {};
  for (int k0 = 0; k0 < DIN; k0 += BK) {
    float4 av = *(const float4*)(x + (size_t)(m0 + arow) * DIN + k0 + ak);
    float4 bv = *(const float4*)(Wi + (size_t)(k0 + bk) * G4 + n0 + bn);
    __syncthreads();
    As[ak + 0][arow] = av.x;
    As[ak + 1][arow] = av.y;
    As[ak + 2][arow] = av.z;
    As[ak + 3][arow] = av.w;
    *(float4*)&Bs[bk][bn] = bv;
    __syncthreads();
#pragma unroll
    for (int kk = 0; kk < BK; ++kk) {
      float am[4], bw[4];
      *(float4*)am = *(const float4*)&As[kk][ty << 2];
      *(float4*)bw = *(const float4*)&Bs[kk][tx << 2];
#pragma unroll
      for (int i = 0; i < 4; ++i)
#pragma unroll
        for (int j = 0; j < 4; ++j) acc[i][j] = fmaf(am[i], bw[j], acc[i][j]);
    }
  }
  // rows m = m0+ty*4+i: t = m>>3, b = (m&7); (m_base&7) in {0,4} so q=i, rg=(m_base&7)>>2
  const int m_base = m0 + (ty << 2);
  const int n_base = n0 + (tx << 2);
  const int tt = m_base >> 3;
  const int rg = (m_base & 7) >> 2;
  const int gate = n_base >> 9;
  const int wv = (n_base & 511) >> 4;
  const int col0 = n_base & 15;
#pragma unroll
  for (int j = 0; j < 4; ++j) {
    int n = n_base + j;
    float bs = bi[n] + bh[n];
    unsigned long long pk = 0;
#pragma unroll
    for (int i = 0; i < 4; ++i)
      pk |= (unsigned long long)f2b(acc[i][j] + bs) << (16 * i);
    int lane = rg * 16 + col0 + j;
    size_t u16idx = (((size_t)tt * NWV + wv) * 32 + lane) * 16 + gate * 4;
    *(unsigned long long*)(xi + u16idx) = pk;
  }
}

// ---------------- persistent recurrence: 32 blocks x 64 threads (1 wave each).
// wave owns cols [wv*16, wv*16+16), all 4 gates. Tag poll (1 atomic/lane) + fences + plain loads.
__global__ __launch_bounds__(64, 1) void lstm_rec(const float* __restrict__ Wh,
                                                  const float* __restrict__ h0c0,
                                                  const unsigned short* __restrict__ xi,
                                                  float* __restrict__ out,
                                                  unsigned int* tags,
                                                  unsigned short* hbuf) {
  const int wv = blockIdx.x;
  const int j0 = wv * JPW;
  const int lane = threadIdx.x;
  const int col = lane & 15;      // C col / A row(batch) / loader col
  const int rg = lane >> 4;       // C row-group / A k-subblock

  __shared__ bf16x8 bwS[4][16][64];   // 64 KiB: frag layout per (gate, ks, lane)

  // ---- prologue: Wh slice -> LDS in frag layout. loader lane: gate gp=lane>>4, col cp=lane&15
  {
    const int gp = lane >> 4, cp = lane & 15;
    const float* wsrc = Wh + (size_t)gp * NH + j0 + cp;
#pragma unroll 4
    for (int k = 0; k < 512; ++k) {
      float wval = wsrc[(size_t)k * G4];
      const int ks = k >> 5, kq = (k >> 3) & 3, e = k & 7;
      ((unsigned short*)&bwS[gp][ks][kq * 16 + cp])[e] = f2b(wval);
    }
  }
  __syncthreads();

  // gates 0,1 cached in VGPRs; gates 2,3 read from LDS each step
  bf16x8 bwR0[16], bwR1[16];
#pragma unroll
  for (int ks = 0; ks < 16; ++ks) {
    bwR0[ks] = bwS[0][ks][lane];
    bwR1[ks] = bwS[1][ks][lane];
  }

  f32x4 cell = {0.f, 0.f, 0.f, 0.f};
  if (lane < 32) {
#pragma unroll
    for (int q = 0; q < 4; ++q)
      cell[q] = h0c0[(size_t)(BATCH + rg * 4 + q) * NH + j0 + col];
  }

  uint4 xiA = {0, 0, 0, 0}, xiB = {0, 0, 0, 0};
  if (lane < 32) {
    const unsigned short* xp = xi + ((size_t)wv * 32 + lane) * 16;
    xiA = *(const uint4*)xp;
    xiB = *(const uint4*)(xp + 8);
  }
  f32x4 hq = {0.f, 0.f, 0.f, 0.f};

  for (int t = 0; t < T_STEPS; ++t) {
    // ---- poll: ONE atomic tag load per lane per retry
    {
      unsigned int tv;
      do {
        tv = __hip_atomic_load(&tags[lane & 31], __ATOMIC_RELAXED, __HIP_MEMORY_SCOPE_AGENT);
      } while (__any((int)tv < t));
    }
    __builtin_amdgcn_fence(__ATOMIC_ACQUIRE, "agent");

    // ---- h(t) A-frags: plain wide loads (parallel, post-fence)
    const unsigned short* mb = hbuf + ((t & 1) << 12);
    bf16x8 af[16];
    if (col < 8) {
      const unsigned short* ap = mb + col * 512 + (rg << 3);
#pragma unroll
      for (int ks = 0; ks < 16; ++ks)
        af[ks] = *(const bf16x8*)(ap + ks * 32);
    } else {
#pragma unroll
      for (int ks = 0; ks < 16; ++ks) {
        bf16x8 z = {0, 0, 0, 0, 0, 0, 0, 0};
        af[ks] = z;
      }
    }

    // ---- acc init from XI
    f32x4 acc[4][2];
    {
      unsigned int wrd[8] = {xiA.x, xiA.y, xiA.z, xiA.w, xiB.x, xiB.y, xiB.z, xiB.w};
      f32x4 z = {0.f, 0.f, 0.f, 0.f};
#pragma unroll
      for (int g = 0; g < 4; ++g) {
#pragma unroll
        for (int q = 0; q < 4; ++q) {
          const int idx = g * 4 + q;
          float s = (lane < 32) ? b2f((unsigned short)(wrd[idx >> 1] >> ((idx & 1) * 16))) : 0.f;
          acc[g][0][q] = s;
        }
        acc[g][1] = z;
      }
    }

    // ---- 64 MFMAs (4 gates x 16 ks, 2 chains/gate)
#pragma unroll
    for (int ks = 0; ks < 16; ++ks) {
      acc[0][ks & 1] = __builtin_amdgcn_mfma_f32_16x16x32_bf16(af[ks], bwR0[ks], acc[0][ks & 1], 0, 0, 0);
      acc[1][ks & 1] = __builtin_amdgcn_mfma_f32_16x16x32_bf16(af[ks], bwR1[ks], acc[1][ks & 1], 0, 0, 0);
      acc[2][ks & 1] = __builtin_amdgcn_mfma_f32_16x16x32_bf16(af[ks], bwS[2][ks][lane], acc[2][ks & 1], 0, 0, 0);
      acc[3][ks & 1] = __builtin_amdgcn_mfma_f32_16x16x32_bf16(af[ks], bwS[3][ks][lane], acc[3][ks & 1], 0, 0, 0);
    }

    // ---- gates (all in-lane; lanes>=32 compute benign zeros)
#pragma unroll
    for (int q = 0; q < 4; ++q) {
      float pf = acc[0][0][q] + acc[0][1][q];
      float pi = acc[1][0][q] + acc[1][1][q];
      float po = acc[2][0][q] + acc[2][1][q];
      float pg = acc[3][0][q] + acc[3][1][q];
      float fg = sigf(pf), ig = sigf(pi), og = sigf(po), gg = tanh_fast(pg);
      float cn = fg * cell[q] + ig * gg;
      cell[q] = cn;
      hq[q] = og * tanh_fast(cn);
    }

    // ---- publish h(t+1) (plain u32 stores) -> release fence -> tag store
    {
      unsigned short* pub = hbuf + (((t + 1) & 1) << 12);
      const int pb = lane >> 3, pjl = lane & 7;
      const int srcA = ((pb >> 2) << 4) + (pjl << 1);
      const int qs = pb & 3;
      float hA = 0.f, hB = 0.f;
#pragma unroll
      for (int qq = 0; qq < 4; ++qq) {
        float sA = __shfl(hq[qq], srcA);
        float sB = __shfl(hq[qq], srcA + 1);
        if (qq == qs) { hA = sA; hB = sB; }
      }
      unsigned int pk = ((unsigned int)f2b(hB) << 16) | f2b(hA);
      *(unsigned int*)(pub + pb * 512 + j0 + (pjl << 1)) = pk;
    }
    __builtin_amdgcn_fence(__ATOMIC_RELEASE, "agent");
    if (lane == 0)
      __hip_atomic_store(&tags[wv], (unsigned int)(t + 1), __ATOMIC_RELAXED,
                         __HIP_MEMORY_SCOPE_AGENT);

    // ---- out stores + XI(t+1) prefetch (off critical path, drain overlaps next poll)
    if (lane < 32) {
#pragma unroll
      for (int q = 0; q < 4; ++q)
        out[((size_t)t * BATCH + (rg * 4 + q)) * NH + j0 + col] = hq[q];
      if (t + 1 < T_STEPS) {
        const unsigned short* xp = xi + (((size_t)(t + 1) * NWV + wv) * 32 + lane) * 16;
        xiA = *(const uint4*)xp;
        xiB = *(const uint4*)(xp + 8);
      }
    }
  }

  // ---- final state tail: [h_T ; c_T]
  if (lane < 32) {
    const size_t tail = (size_t)T_STEPS * BATCH * NH;
#pragma unroll
    for (int q = 0; q < 4; ++q) {
      out[tail + (size_t)(rg * 4 + q) * NH + j0 + col] = hq[q];
      out[tail + (size_t)BATCH * NH + (size_t)(rg * 4 + q) * NH + j0 + col] = cell[q];
    }
  }
}

extern "C" void kernel_launch(void* const* d_in, const int* in_sizes, int n_in,
                              void* d_out, int out_size, void* d_ws, size_t ws_size,
                              hipStream_t stream) {
  const float* x  = (const float*)d_in[0];
  const float* h0 = (const float*)d_in[1];
  const float* Wi = (const float*)d_in[2];
  const float* bi = (const float*)d_in[3];
  const float* Wh = (const float*)d_in[4];
  const float* bh = (const float*)d_in[5];
  float* out = (float*)d_out;

  // ws: [0,128) tags u32[32] | [256, +16KB) hbuf u16[2][8][512] | [64KB, +64MB) xi u16
  unsigned int* tags = (unsigned int*)d_ws;
  unsigned short* hbuf = (unsigned short*)((char*)d_ws + 256);
  unsigned short* xi = (unsigned short*)((char*)d_ws + 65536);

  init_ws<<<1, 512, 0, stream>>>(h0, tags, hbuf);
  dim3 g1((T_STEPS * BATCH) / BM, G4 / BN);
  xi_gemm<<<g1, 256, 0, stream>>>(x, Wi, bi, bh, xi);
  lstm_rec<<<NWV, 64, 0, stream>>>(Wh, h0, xi, out, tags, hbuf);
}

// Round 4
// 15289.432 us; speedup vs baseline: 8.5408x; 1.2831x over previous
//
#include <hip/hip_runtime.h>
#include <hip/hip_bf16.h>

#define T_STEPS 4096
#define BATCH 8
#define DIN 512
#define NH 512
#define G4 2048
#define NWV 32
#define JPW 16

typedef __attribute__((ext_vector_type(8))) short bf16x8;
typedef __attribute__((ext_vector_type(4))) float f32x4;
typedef __attribute__((ext_vector_type(4))) int i32x4;

__device__ __forceinline__ unsigned short f2b(float f) {
  __hip_bfloat16 h = __float2bfloat16(f);
  return __builtin_bit_cast(unsigned short, h);
}
__device__ __forceinline__ float b2f(unsigned short u) {
  unsigned int x = ((unsigned int)u) << 16;
  return __builtin_bit_cast(float, x);
}
__device__ __forceinline__ float sigf(float x) { return 1.f / (1.f + __expf(-x)); }
__device__ __forceinline__ float tanh_fast(float x) { return 1.f - 2.f / (1.f + __expf(2.f * x)); }

// ---------------- init: tags=0; hbuf parity0 = bf16(h0), parity1 = 0
__global__ __launch_bounds__(512) void init_ws(const float* __restrict__ h0,
                                               unsigned int* __restrict__ tags,
                                               unsigned short* __restrict__ hbuf) {
  int tid = threadIdx.x;
  if (tid < NWV) tags[tid] = 0u;
  for (int i = tid; i < 4096; i += 512) {   // [8 b][512 j] per parity
    int b = i >> 9, j = i & 511;
    hbuf[i] = f2b(h0[b * NH + j]);
    hbuf[4096 + i] = 0;
  }
}

// ---------------- XI = x @ Wi + (bi + bh), swizzled to [t][wv][lane(32)][g*4+q] u16
#define BM 64
#define BN 64
#define BK 16
__global__ __launch_bounds__(256) void xi_gemm(const float* __restrict__ x,
                                               const float* __restrict__ Wi,
                                               const float* __restrict__ bi,
                                               const float* __restrict__ bh,
                                               unsigned short* __restrict__ xi) {
  __shared__ float As[BK][BM + 4];
  __shared__ float Bs[BK][BN + 4];
  const int tid = threadIdx.x;
  const int m0 = blockIdx.x * BM;
  const int n0 = blockIdx.y * BN;
  const int tx = tid & 15, ty = tid >> 4;
  const int arow = tid & 63, ak = (tid >> 6) << 2;
  const int bk = tid >> 4, bn = (tid & 15) << 2;
  float acc[4][4] = {};
  for (int k0 = 0; k0 < DIN; k0 += BK) {
    float4 av = *(const float4*)(x + (size_t)(m0 + arow) * DIN + k0 + ak);
    float4 bv = *(const float4*)(Wi + (size_t)(k0 + bk) * G4 + n0 + bn);
    __syncthreads();
    As[ak + 0][arow] = av.x;
    As[ak + 1][arow] = av.y;
    As[ak + 2][arow] = av.z;
    As[ak + 3][arow] = av.w;
    *(float4*)&Bs[bk][bn] = bv;
    __syncthreads();
#pragma unroll
    for (int kk = 0; kk < BK; ++kk) {
      float am[4], bw[4];
      *(float4*)am = *(const float4*)&As[kk][ty << 2];
      *(float4*)bw = *(const float4*)&Bs[kk][tx << 2];
#pragma unroll
      for (int i = 0; i < 4; ++i)
#pragma unroll
        for (int j = 0; j < 4; ++j) acc[i][j] = fmaf(am[i], bw[j], acc[i][j]);
    }
  }
  const int m_base = m0 + (ty << 2);
  const int n_base = n0 + (tx << 2);
  const int tt = m_base >> 3;
  const int rg = (m_base & 7) >> 2;
  const int gate = n_base >> 9;
  const int wv = (n_base & 511) >> 4;
  const int col0 = n_base & 15;
#pragma unroll
  for (int j = 0; j < 4; ++j) {
    int n = n_base + j;
    float bs = bi[n] + bh[n];
    unsigned long long pk = 0;
#pragma unroll
    for (int i = 0; i < 4; ++i)
      pk |= (unsigned long long)f2b(acc[i][j] + bs) << (16 * i);
    int lane = rg * 16 + col0 + j;
    size_t u16idx = (((size_t)tt * NWV + wv) * 32 + lane) * 16 + gate * 4;
    *(unsigned long long*)(xi + u16idx) = pk;
  }
}

// ---------------- persistent recurrence: 32 blocks x 64 threads (1 wave each).
// Protocol: LLC-coherent (sc0 sc1) stores+tag / poll+loads. No fences, no wbl2/inv.
__global__ __launch_bounds__(64, 1) void lstm_rec(const float* __restrict__ Wh,
                                                  const float* __restrict__ h0c0,
                                                  const unsigned short* __restrict__ xi,
                                                  float* __restrict__ out,
                                                  unsigned int* tags,
                                                  unsigned short* hbuf) {
  const int wv = blockIdx.x;
  const int j0 = wv * JPW;
  const int lane = threadIdx.x;
  const int col = lane & 15;      // C col / loader batch-row
  const int rg = lane >> 4;       // C row-group / A k-subblock

  __shared__ bf16x8 bwS[4][16][64];   // 64 KiB frag-layout Wh slice

  // ---- prologue: Wh slice -> LDS in frag layout
  {
    const int gp = lane >> 4, cp = lane & 15;
    const float* wsrc = Wh + (size_t)gp * NH + j0 + cp;
#pragma unroll 4
    for (int k = 0; k < 512; ++k) {
      float wval = wsrc[(size_t)k * G4];
      const int ks = k >> 5, kq = (k >> 3) & 3, e = k & 7;
      ((unsigned short*)&bwS[gp][ks][kq * 16 + cp])[e] = f2b(wval);
    }
  }
  __syncthreads();

  bf16x8 bwR0[16], bwR1[16];
#pragma unroll
  for (int ks = 0; ks < 16; ++ks) {
    bwR0[ks] = bwS[0][ks][lane];
    bwR1[ks] = bwS[1][ks][lane];
  }

  f32x4 cell = {0.f, 0.f, 0.f, 0.f};
  if (lane < 32) {
#pragma unroll
    for (int q = 0; q < 4; ++q)
      cell[q] = h0c0[(size_t)(BATCH + rg * 4 + q) * NH + j0 + col];
  }

  // ---- XI(0) preload (plain loads, drained by first h-wait)
  i32x4 xiC0, xiC1, xiN0, xiN1;
  {
    const unsigned short* xp = xi + ((size_t)wv * 32 + (lane & 31)) * 16;
    xiC0 = *(const i32x4*)xp;
    xiC1 = *(const i32x4*)(xp + 8);
  }
  f32x4 hq = {0.f, 0.f, 0.f, 0.f};

  const unsigned int* tp = tags + (lane & 31);
  unsigned int* myTag = tags + wv;

  for (int t = 0; t < T_STEPS; ++t) {
    // ---- (1) poll: one LLC dword per lane per retry
    {
      unsigned int tv;
      do {
        asm volatile("global_load_dword %0, %1, off sc0 sc1\n\ts_waitcnt vmcnt(0)"
                     : "=v"(tv) : "v"(tp) : "memory");
      } while (__any((int)tv < t));
    }

    // ---- (2) h(t): 16 pipelined LLC dwordx4 loads (clamped, no divergence)
    const unsigned short* mb = hbuf + ((t & 1) << 12);
    const unsigned short* ap = mb + (col & 7) * 512 + (rg << 3);
    i32x4 afr[16];
    asm volatile("global_load_dwordx4 %0, %1, off sc0 sc1" : "=v"(afr[0]) : "v"(ap));
    asm volatile("global_load_dwordx4 %0, %1, off offset:64 sc0 sc1" : "=v"(afr[1]) : "v"(ap));
    asm volatile("global_load_dwordx4 %0, %1, off offset:128 sc0 sc1" : "=v"(afr[2]) : "v"(ap));
    asm volatile("global_load_dwordx4 %0, %1, off offset:192 sc0 sc1" : "=v"(afr[3]) : "v"(ap));
    asm volatile("global_load_dwordx4 %0, %1, off offset:256 sc0 sc1" : "=v"(afr[4]) : "v"(ap));
    asm volatile("global_load_dwordx4 %0, %1, off offset:320 sc0 sc1" : "=v"(afr[5]) : "v"(ap));
    asm volatile("global_load_dwordx4 %0, %1, off offset:384 sc0 sc1" : "=v"(afr[6]) : "v"(ap));
    asm volatile("global_load_dwordx4 %0, %1, off offset:448 sc0 sc1" : "=v"(afr[7]) : "v"(ap));
    asm volatile("global_load_dwordx4 %0, %1, off offset:512 sc0 sc1" : "=v"(afr[8]) : "v"(ap));
    asm volatile("global_load_dwordx4 %0, %1, off offset:576 sc0 sc1" : "=v"(afr[9]) : "v"(ap));
    asm volatile("global_load_dwordx4 %0, %1, off offset:640 sc0 sc1" : "=v"(afr[10]) : "v"(ap));
    asm volatile("global_load_dwordx4 %0, %1, off offset:704 sc0 sc1" : "=v"(afr[11]) : "v"(ap));
    asm volatile("global_load_dwordx4 %0, %1, off offset:768 sc0 sc1" : "=v"(afr[12]) : "v"(ap));
    asm volatile("global_load_dwordx4 %0, %1, off offset:832 sc0 sc1" : "=v"(afr[13]) : "v"(ap));
    asm volatile("global_load_dwordx4 %0, %1, off offset:896 sc0 sc1" : "=v"(afr[14]) : "v"(ap));
    asm volatile("global_load_dwordx4 %0, %1, off offset:960 sc0 sc1" : "=v"(afr[15]) : "v"(ap));
    // ---- (3) wait for h data; fence the scheduler (rule #18)
    asm volatile("s_waitcnt vmcnt(0)" ::: "memory");
    __builtin_amdgcn_sched_barrier(0);

    // ---- (4) XI(t+1) prefetch (plain; hidden under MFMA+gates, drained at (9))
    {
      const int tn = (t + 1 < T_STEPS) ? (t + 1) : t;
      const unsigned short* xp = xi + (((size_t)tn * NWV + wv) * 32 + (lane & 31)) * 16;
      asm volatile("global_load_dwordx4 %0, %1, off" : "=v"(xiN0) : "v"(xp));
      asm volatile("global_load_dwordx4 %0, %1, off offset:16" : "=v"(xiN1) : "v"(xp));
    }

    // ---- (5) acc seed from XI + 64 MFMAs
    f32x4 acc[4][2];
    {
      unsigned int wrd[8] = {(unsigned int)xiC0[0], (unsigned int)xiC0[1],
                             (unsigned int)xiC0[2], (unsigned int)xiC0[3],
                             (unsigned int)xiC1[0], (unsigned int)xiC1[1],
                             (unsigned int)xiC1[2], (unsigned int)xiC1[3]};
      f32x4 z = {0.f, 0.f, 0.f, 0.f};
#pragma unroll
      for (int g = 0; g < 4; ++g) {
#pragma unroll
        for (int q = 0; q < 4; ++q) {
          const int idx = g * 4 + q;
          acc[g][0][q] = b2f((unsigned short)(wrd[idx >> 1] >> ((idx & 1) * 16)));
        }
        acc[g][1] = z;
      }
    }
#pragma unroll
    for (int ks = 0; ks < 16; ++ks) {
      bf16x8 a = __builtin_bit_cast(bf16x8, afr[ks]);
      acc[0][ks & 1] = __builtin_amdgcn_mfma_f32_16x16x32_bf16(a, bwR0[ks], acc[0][ks & 1], 0, 0, 0);
      acc[1][ks & 1] = __builtin_amdgcn_mfma_f32_16x16x32_bf16(a, bwR1[ks], acc[1][ks & 1], 0, 0, 0);
      acc[2][ks & 1] = __builtin_amdgcn_mfma_f32_16x16x32_bf16(a, bwS[2][ks][lane], acc[2][ks & 1], 0, 0, 0);
      acc[3][ks & 1] = __builtin_amdgcn_mfma_f32_16x16x32_bf16(a, bwS[3][ks][lane], acc[3][ks & 1], 0, 0, 0);
    }

    // ---- (6) gates
#pragma unroll
    for (int q = 0; q < 4; ++q) {
      float pf = acc[0][0][q] + acc[0][1][q];
      float pi = acc[1][0][q] + acc[1][1][q];
      float po = acc[2][0][q] + acc[2][1][q];
      float pg = acc[3][0][q] + acc[3][1][q];
      float fg = sigf(pf), ig = sigf(pi), og = sigf(po), gg = tanh_fast(pg);
      float cn = fg * cell[q] + ig * gg;
      cell[q] = cn;
      hq[q] = og * tanh_fast(cn);
    }

    if (lane < 32) {
      // ---- (7) out stores (plain -> local L2 ack, covered by drain (9))
#pragma unroll
      for (int q = 0; q < 4; ++q)
        out[((size_t)t * BATCH + (rg * 4 + q)) * NH + j0 + col] = hq[q];
      // ---- (8) publish h(t+1): 4 LLC u16 stores per lane (own values, no shuffles)
      unsigned short* pp = hbuf + (((t + 1) & 1) << 12) + (rg * 4) * 512 + j0 + col;
      unsigned int h0u = f2b(hq[0]), h1u = f2b(hq[1]), h2u = f2b(hq[2]), h3u = f2b(hq[3]);
      asm volatile("global_store_short %0, %1, off sc0 sc1" :: "v"(pp), "v"(h0u) : "memory");
      asm volatile("global_store_short %0, %1, off offset:1024 sc0 sc1" :: "v"(pp), "v"(h1u) : "memory");
      asm volatile("global_store_short %0, %1, off offset:2048 sc0 sc1" :: "v"(pp), "v"(h2u) : "memory");
      asm volatile("global_store_short %0, %1, off offset:3072 sc0 sc1" :: "v"(pp), "v"(h3u) : "memory");
    }
    // ---- (9) drain (publish acks at LLC; out/XI cheap or overlapped)
    asm volatile("s_waitcnt vmcnt(0)" ::: "memory");
    // ---- (10) tag store
    if (lane == 0) {
      unsigned int tn1 = (unsigned int)(t + 1);
      asm volatile("global_store_dword %0, %1, off sc0 sc1" :: "v"(myTag), "v"(tn1) : "memory");
    }
    xiC0 = xiN0;
    xiC1 = xiN1;
  }

  // ---- final state tail: [h_T ; c_T]
  if (lane < 32) {
    const size_t tail = (size_t)T_STEPS * BATCH * NH;
#pragma unroll
    for (int q = 0; q < 4; ++q) {
      out[tail + (size_t)(rg * 4 + q) * NH + j0 + col] = hq[q];
      out[tail + (size_t)BATCH * NH + (size_t)(rg * 4 + q) * NH + j0 + col] = cell[q];
    }
  }
}

extern "C" void kernel_launch(void* const* d_in, const int* in_sizes, int n_in,
                              void* d_out, int out_size, void* d_ws, size_t ws_size,
                              hipStream_t stream) {
  const float* x  = (const float*)d_in[0];
  const float* h0 = (const float*)d_in[1];
  const float* Wi = (const float*)d_in[2];
  const float* bi = (const float*)d_in[3];
  const float* Wh = (const float*)d_in[4];
  const float* bh = (const float*)d_in[5];
  float* out = (float*)d_out;

  unsigned int* tags = (unsigned int*)d_ws;
  unsigned short* hbuf = (unsigned short*)((char*)d_ws + 256);
  unsigned short* xi = (unsigned short*)((char*)d_ws + 65536);

  init_ws<<<1, 512, 0, stream>>>(h0, tags, hbuf);
  dim3 g1((T_STEPS * BATCH) / BM, G4 / BN);
  xi_gemm<<<g1, 256, 0, stream>>>(x, Wi, bi, bh, xi);
  lstm_rec<<<NWV, 64, 0, stream>>>(Wh, h0, xi, out, tags, hbuf);
}

// Round 8
// 15107.712 us; speedup vs baseline: 8.6435x; 1.0120x over previous
//
#include <hip/hip_runtime.h>
#include <hip/hip_bf16.h>

#define T_STEPS 4096
#define BATCH 8
#define DIN 512
#define NH 512
#define G4 2048
#define NWV 32
#define JPW 16

typedef __attribute__((ext_vector_type(8))) short bf16x8;
typedef __attribute__((ext_vector_type(4))) float f32x4;
typedef __attribute__((ext_vector_type(4))) int i32x4;

__device__ __forceinline__ unsigned short f2b(float f) {
  __hip_bfloat16 h = __float2bfloat16(f);
  return __builtin_bit_cast(unsigned short, h);
}
__device__ __forceinline__ float b2f(unsigned short u) {
  unsigned int x = ((unsigned int)u) << 16;
  return __builtin_bit_cast(float, x);
}
__device__ __forceinline__ float sigf(float x) { return 1.f / (1.f + __expf(-x)); }
__device__ __forceinline__ float tanh_fast(float x) { return 1.f - 2.f / (1.f + __expf(2.f * x)); }

// ---------------- init: tags=0; hbuf parity0 = bf16(h0), parity1 = 0
__global__ __launch_bounds__(512) void init_ws(const float* __restrict__ h0,
                                               unsigned int* __restrict__ tags,
                                               unsigned short* __restrict__ hbuf) {
  int tid = threadIdx.x;
  if (tid < NWV) tags[tid] = 0u;
  for (int i = tid; i < 4096; i += 512) {   // [8 b][512 j] per parity
    int b = i >> 9, j = i & 511;
    hbuf[i] = f2b(h0[b * NH + j]);
    hbuf[4096 + i] = 0;
  }
}

// ---------------- XI = x @ Wi + (bi + bh), swizzled to [t][wv][lane(32)][g*4+q] u16
#define BM 64
#define BN 64
#define BK 16
__global__ __launch_bounds__(256) void xi_gemm(const float* __restrict__ x,
                                               const float* __restrict__ Wi,
                                               const float* __restrict__ bi,
                                               const float* __restrict__ bh,
                                               unsigned short* __restrict__ xi) {
  __shared__ float As[BK][BM + 4];
  __shared__ float Bs[BK][BN + 4];
  const int tid = threadIdx.x;
  const int m0 = blockIdx.x * BM;
  const int n0 = blockIdx.y * BN;
  const int tx = tid & 15, ty = tid >> 4;
  const int arow = tid & 63, ak = (tid >> 6) << 2;
  const int bk = tid >> 4, bn = (tid & 15) << 2;
  float acc[4][4] = {};
  for (int k0 = 0; k0 < DIN; k0 += BK) {
    float4 av = *(const float4*)(x + (size_t)(m0 + arow) * DIN + k0 + ak);
    float4 bv = *(const float4*)(Wi + (size_t)(k0 + bk) * G4 + n0 + bn);
    __syncthreads();
    As[ak + 0][arow] = av.x;
    As[ak + 1][arow] = av.y;
    As[ak + 2][arow] = av.z;
    As[ak + 3][arow] = av.w;
    *(float4*)&Bs[bk][bn] = bv;
    __syncthreads();
#pragma unroll
    for (int kk = 0; kk < BK; ++kk) {
      float am[4], bw[4];
      *(float4*)am = *(const float4*)&As[kk][ty << 2];
      *(float4*)bw = *(const float4*)&Bs[kk][tx << 2];
#pragma unroll
      for (int i = 0; i < 4; ++i)
#pragma unroll
        for (int j = 0; j < 4; ++j) acc[i][j] = fmaf(am[i], bw[j], acc[i][j]);
    }
  }
  const int m_base = m0 + (ty << 2);
  const int n_base = n0 + (tx << 2);
  const int tt = m_base >> 3;
  const int rg = (m_base & 7) >> 2;
  const int gate = n_base >> 9;
  const int wv = (n_base & 511) >> 4;
  const int col0 = n_base & 15;
#pragma unroll
  for (int j = 0; j < 4; ++j) {
    int n = n_base + j;
    float bs = bi[n] + bh[n];
    unsigned long long pk = 0;
#pragma unroll
    for (int i = 0; i < 4; ++i)
      pk |= (unsigned long long)f2b(acc[i][j] + bs) << (16 * i);
    int lane = rg * 16 + col0 + j;
    size_t u16idx = (((size_t)tt * NWV + wv) * 32 + lane) * 16 + gate * 4;
    *(unsigned long long*)(xi + u16idx) = pk;
  }
}

// ---------------- persistent recurrence: 32 blocks x 64 threads (1 wave each).
// R4-proven protocol: sc0sc1 tag poll -> sc0sc1 data burst -> compute ->
// sc0sc1 publish -> vmcnt(0) -> sc0sc1 tag store. Changes vs R4: no acquire
// fence (data loads are LLC-direct anyway); out-stores + XI prefetch moved
// AFTER the tag store (their HBM acks overlap the next poll instead of
// sitting in the pre-tag drain).
__global__ __launch_bounds__(64, 1) void lstm_rec(const float* __restrict__ Wh,
                                                  const float* __restrict__ h0c0,
                                                  const unsigned short* __restrict__ xi,
                                                  float* __restrict__ out,
                                                  unsigned int* tags,
                                                  unsigned short* hbuf) {
  const int wv = blockIdx.x;
  const int j0 = wv * JPW;
  const int lane = threadIdx.x;
  const int col = lane & 15;      // C col / loader batch-row
  const int rg = lane >> 4;       // C row-group / A k-subblock

  __shared__ bf16x8 bwS[4][16][64];   // 64 KiB frag-layout Wh slice

  // ---- prologue: Wh slice -> LDS in frag layout
  {
    const int gp = lane >> 4, cp = lane & 15;
    const float* wsrc = Wh + (size_t)gp * NH + j0 + cp;
#pragma unroll 4
    for (int k = 0; k < 512; ++k) {
      float wval = wsrc[(size_t)k * G4];
      const int ks = k >> 5, kq = (k >> 3) & 3, e = k & 7;
      ((unsigned short*)&bwS[gp][ks][kq * 16 + cp])[e] = f2b(wval);
    }
  }
  __syncthreads();

  bf16x8 bwR0[16], bwR1[16];
#pragma unroll
  for (int ks = 0; ks < 16; ++ks) {
    bwR0[ks] = bwS[0][ks][lane];
    bwR1[ks] = bwS[1][ks][lane];
  }

  f32x4 cell = {0.f, 0.f, 0.f, 0.f};
  if (lane < 32) {
#pragma unroll
    for (int q = 0; q < 4; ++q)
      cell[q] = h0c0[(size_t)(BATCH + rg * 4 + q) * NH + j0 + col];
  }

  // ---- XI(0) preload
  i32x4 xiC0, xiC1, xiN0, xiN1;
  {
    const unsigned short* xp = xi + ((size_t)wv * 32 + (lane & 31)) * 16;
    asm volatile("global_load_dwordx4 %0, %1, off" : "=&v"(xiC0) : "v"(xp));
    asm volatile("global_load_dwordx4 %0, %1, off offset:16" : "=&v"(xiC1) : "v"(xp));
  }
  f32x4 hq = {0.f, 0.f, 0.f, 0.f};

  const unsigned int* tp = tags + (lane & 31);
  unsigned int* myTag = tags + wv;

  for (int t = 0; t < T_STEPS; ++t) {
    // ---- (1) poll: one LLC dword per lane per retry (R4-proven; also drains
    //      the previous step's post-tag out/XI traffic in parallel with tag wait)
    {
      unsigned int tv;
      do {
        asm volatile("global_load_dword %0, %1, off sc0 sc1\n\ts_waitcnt vmcnt(0)"
                     : "=v"(tv) : "v"(tp) : "memory");
      } while (__any((int)tv < t));
    }

    // ---- (2) h(t): 16 pipelined LLC dwordx4 loads (clamped, no divergence)
    const unsigned short* mb = hbuf + ((t & 1) << 12);
    const unsigned short* ap = mb + (col & 7) * 512 + (rg << 3);
    i32x4 afr[16];
    asm volatile("global_load_dwordx4 %0, %1, off sc0 sc1" : "=v"(afr[0]) : "v"(ap));
    asm volatile("global_load_dwordx4 %0, %1, off offset:64 sc0 sc1" : "=v"(afr[1]) : "v"(ap));
    asm volatile("global_load_dwordx4 %0, %1, off offset:128 sc0 sc1" : "=v"(afr[2]) : "v"(ap));
    asm volatile("global_load_dwordx4 %0, %1, off offset:192 sc0 sc1" : "=v"(afr[3]) : "v"(ap));
    asm volatile("global_load_dwordx4 %0, %1, off offset:256 sc0 sc1" : "=v"(afr[4]) : "v"(ap));
    asm volatile("global_load_dwordx4 %0, %1, off offset:320 sc0 sc1" : "=v"(afr[5]) : "v"(ap));
    asm volatile("global_load_dwordx4 %0, %1, off offset:384 sc0 sc1" : "=v"(afr[6]) : "v"(ap));
    asm volatile("global_load_dwordx4 %0, %1, off offset:448 sc0 sc1" : "=v"(afr[7]) : "v"(ap));
    asm volatile("global_load_dwordx4 %0, %1, off offset:512 sc0 sc1" : "=v"(afr[8]) : "v"(ap));
    asm volatile("global_load_dwordx4 %0, %1, off offset:576 sc0 sc1" : "=v"(afr[9]) : "v"(ap));
    asm volatile("global_load_dwordx4 %0, %1, off offset:640 sc0 sc1" : "=v"(afr[10]) : "v"(ap));
    asm volatile("global_load_dwordx4 %0, %1, off offset:704 sc0 sc1" : "=v"(afr[11]) : "v"(ap));
    asm volatile("global_load_dwordx4 %0, %1, off offset:768 sc0 sc1" : "=v"(afr[12]) : "v"(ap));
    asm volatile("global_load_dwordx4 %0, %1, off offset:832 sc0 sc1" : "=v"(afr[13]) : "v"(ap));
    asm volatile("global_load_dwordx4 %0, %1, off offset:896 sc0 sc1" : "=v"(afr[14]) : "v"(ap));
    asm volatile("global_load_dwordx4 %0, %1, off offset:960 sc0 sc1" : "=v"(afr[15]) : "v"(ap));
    // ---- (3) wait for h data; fence the scheduler (rule #18)
    asm volatile("s_waitcnt vmcnt(0)" ::: "memory");
    __builtin_amdgcn_sched_barrier(0);

    // ---- (4) acc seed from XI + 64 MFMAs
    f32x4 acc[4][2];
    {
      unsigned int wrd[8] = {(unsigned int)xiC0[0], (unsigned int)xiC0[1],
                             (unsigned int)xiC0[2], (unsigned int)xiC0[3],
                             (unsigned int)xiC1[0], (unsigned int)xiC1[1],
                             (unsigned int)xiC1[2], (unsigned int)xiC1[3]};
      f32x4 z = {0.f, 0.f, 0.f, 0.f};
#pragma unroll
      for (int g = 0; g < 4; ++g) {
#pragma unroll
        for (int q = 0; q < 4; ++q) {
          const int idx = g * 4 + q;
          acc[g][0][q] = b2f((unsigned short)(wrd[idx >> 1] >> ((idx & 1) * 16)));
        }
        acc[g][1] = z;
      }
    }
#pragma unroll
    for (int ks = 0; ks < 16; ++ks) {
      bf16x8 a = __builtin_bit_cast(bf16x8, afr[ks]);
      acc[0][ks & 1] = __builtin_amdgcn_mfma_f32_16x16x32_bf16(a, bwR0[ks], acc[0][ks & 1], 0, 0, 0);
      acc[1][ks & 1] = __builtin_amdgcn_mfma_f32_16x16x32_bf16(a, bwR1[ks], acc[1][ks & 1], 0, 0, 0);
      acc[2][ks & 1] = __builtin_amdgcn_mfma_f32_16x16x32_bf16(a, bwS[2][ks][lane], acc[2][ks & 1], 0, 0, 0);
      acc[3][ks & 1] = __builtin_amdgcn_mfma_f32_16x16x32_bf16(a, bwS[3][ks][lane], acc[3][ks & 1], 0, 0, 0);
    }

    // ---- (5) gates
#pragma unroll
    for (int q = 0; q < 4; ++q) {
      float pf = acc[0][0][q] + acc[0][1][q];
      float pi = acc[1][0][q] + acc[1][1][q];
      float po = acc[2][0][q] + acc[2][1][q];
      float pg = acc[3][0][q] + acc[3][1][q];
      float fg = sigf(pf), ig = sigf(pi), og = sigf(po), gg = tanh_fast(pg);
      float cn = fg * cell[q] + ig * gg;
      cell[q] = cn;
      hq[q] = og * tanh_fast(cn);
    }

    // ---- (6) publish h(t+1): 4 LLC u16 stores per lane (own values, R4-proven)
    if (lane < 32) {
      unsigned short* pp = hbuf + (((t + 1) & 1) << 12) + (rg * 4) * 512 + j0 + col;
      unsigned int h0u = f2b(hq[0]), h1u = f2b(hq[1]), h2u = f2b(hq[2]), h3u = f2b(hq[3]);
      asm volatile("global_store_short %0, %1, off sc0 sc1" :: "v"(pp), "v"(h0u) : "memory");
      asm volatile("global_store_short %0, %1, off offset:1024 sc0 sc1" :: "v"(pp), "v"(h1u) : "memory");
      asm volatile("global_store_short %0, %1, off offset:2048 sc0 sc1" :: "v"(pp), "v"(h2u) : "memory");
      asm volatile("global_store_short %0, %1, off offset:3072 sc0 sc1" :: "v"(pp), "v"(h3u) : "memory");
    }
    // ---- (7) drain publish (LLC acks only — nothing else outstanding)
    asm volatile("s_waitcnt vmcnt(0)" ::: "memory");
    // ---- (8) tag store
    if (lane == 0) {
      unsigned int tn1 = (unsigned int)(t + 1);
      asm volatile("global_store_dword %0, %1, off sc0 sc1" :: "v"(myTag), "v"(tn1) : "memory");
    }

    // ---- (9) POST-tag: out stores + XI(t+1) prefetch (acks/latency overlap next poll)
    if (lane < 32) {
#pragma unroll
      for (int q = 0; q < 4; ++q)
        out[((size_t)t * BATCH + (rg * 4 + q)) * NH + j0 + col] = hq[q];
    }
    {
      const int tn = (t + 1 < T_STEPS) ? (t + 1) : t;
      const unsigned short* xp = xi + (((size_t)tn * NWV + wv) * 32 + (lane & 31)) * 16;
      asm volatile("global_load_dwordx4 %0, %1, off" : "=&v"(xiN0) : "v"(xp));
      asm volatile("global_load_dwordx4 %0, %1, off offset:16" : "=&v"(xiN1) : "v"(xp));
    }
    xiC0 = xiN0;
    xiC1 = xiN1;
  }

  // ---- final state tail: [h_T ; c_T]
  if (lane < 32) {
    const size_t tail = (size_t)T_STEPS * BATCH * NH;
#pragma unroll
    for (int q = 0; q < 4; ++q) {
      out[tail + (size_t)(rg * 4 + q) * NH + j0 + col] = hq[q];
      out[tail + (size_t)BATCH * NH + (size_t)(rg * 4 + q) * NH + j0 + col] = cell[q];
    }
  }
}

extern "C" void kernel_launch(void* const* d_in, const int* in_sizes, int n_in,
                              void* d_out, int out_size, void* d_ws, size_t ws_size,
                              hipStream_t stream) {
  const float* x  = (const float*)d_in[0];
  const float* h0 = (const float*)d_in[1];
  const float* Wi = (const float*)d_in[2];
  const float* bi = (const float*)d_in[3];
  const float* Wh = (const float*)d_in[4];
  const float* bh = (const float*)d_in[5];
  float* out = (float*)d_out;

  unsigned int* tags = (unsigned int*)d_ws;
  unsigned short* hbuf = (unsigned short*)((char*)d_ws + 256);
  unsigned short* xi = (unsigned short*)((char*)d_ws + 65536);

  init_ws<<<1, 512, 0, stream>>>(h0, tags, hbuf);
  dim3 g1((T_STEPS * BATCH) / BM, G4 / BN);
  xi_gemm<<<g1, 256, 0, stream>>>(x, Wi, bi, bh, xi);
  lstm_rec<<<NWV, 64, 0, stream>>>(Wh, h0, xi, out, tags, hbuf);
}